// Round 3
// baseline (115.737 us; speedup 1.0000x reference)
//
#include <hip/hip_runtime.h>

#define NF 7
#define NR 128
#define ROWS 32   // rows per block

__global__ __launch_bounds__(256) void anfis_kernel(
    const float* __restrict__ x,
    const float* __restrict__ mu_g,  const float* __restrict__ sig_g,
    const float* __restrict__ ta, const float* __restrict__ tb,
    const float* __restrict__ tc, const float* __restrict__ td,
    const float* __restrict__ mf_mix, const float* __restrict__ tnw,
    const float* __restrict__ consequent,   // [128][8]
    const int*   __restrict__ rule_idx,     // [128][7]
    float* __restrict__ out,                // [B]
    float* __restrict__ nf_out,             // [B][128]
    float* __restrict__ mem_out,            // [B][14]
    int nrows)
{
    __shared__ float s_x[ROWS][8];          // [1, x0..x6]
    __shared__ float s_mem[ROWS][16];       // 14 used
    __shared__ unsigned int s_mask32[32];   // 128 rule masks packed 4/word

    const int tid  = threadIdx.x;
    const int base = blockIdx.x * ROWS;

    // ---- phase A: rule masks (once per block) ----
    if (tid < NR) {
        int m = 0;
        #pragma unroll
        for (int i = 0; i < NF; ++i)
            if (rule_idx[tid * NF + i] != 0) m |= (1 << i);
        ((unsigned char*)s_mask32)[tid] = (unsigned char)m;
    }

    const float alpha = 1.0f / (1.0f + __expf(-mf_mix[0]));
    const float w     = 1.0f / (1.0f + __expf(-tnw[0]));
    const float a1 = 1.0f - alpha, w1 = 1.0f - w;

    // ---- phase B: all 32 rows' memberships up front (2 rows/thread) ----
    {
        const int j   = tid & 15;
        const int r16 = tid >> 4;

        float mu_j = 0.f, i2s2 = 0.f, q0 = 0.f, q1 = 0.f, q2 = 0.f, q3 = 0.f;
        float invL = 0.f, invR = 0.f;
        if (j < 14) {
            mu_j = mu_g[j];
            float sg = fmaxf(sig_g[j], 1e-6f);
            i2s2 = 1.0f / (2.0f * sg * sg);
            float p0 = ta[j], p1 = tb[j], p2 = tc[j], p3 = td[j];
            float lo, hi;
            lo = fminf(p0, p1); hi = fmaxf(p0, p1); p0 = lo; p1 = hi;
            lo = fminf(p2, p3); hi = fmaxf(p2, p3); p2 = lo; p3 = hi;
            lo = fminf(p0, p2); hi = fmaxf(p0, p2); p0 = lo; p2 = hi;
            lo = fminf(p1, p3); hi = fmaxf(p1, p3); p1 = lo; p3 = hi;
            lo = fminf(p1, p2); hi = fmaxf(p1, p2); p1 = lo; p2 = hi;
            q0 = p0; q1 = p1; q2 = p2; q3 = p3;
            invL = 1.0f / (p1 - p0 + 1e-6f);
            invR = 1.0f / (p3 - p2 + 1e-6f);
        }

        #pragma unroll
        for (int h = 0; h < 2; ++h) {
            const int rl  = r16 + 16 * h;
            const int row = base + rl;
            const bool live = (row < nrows);
            if (j < 14) {
                const float xi = live ? x[row * NF + (j >> 1)] : 0.0f;
                const float dm = xi - mu_j;
                const float gauss = __expf(-(dm * dm) * i2s2);
                float left = (xi - q0) * invL;
                left = fminf(fmaxf(left, 0.f), 1.f);
                const float flat = (xi >= q1 && xi <= q2) ? 1.f : 0.f;
                float right = (q3 - xi) * invR;
                right = fminf(fmaxf(right, 0.f), 1.f);
                const float trap = fmaxf(fminf(left, right), flat);
                const float m = fmaf(alpha, gauss, a1 * trap);
                s_mem[rl][j] = m;
                if (live) mem_out[row * 14 + j] = m;
                if ((j & 1) == 0) s_x[rl][1 + (j >> 1)] = xi;   // even j stages x
            } else if (j == 15) {
                s_x[rl][0] = 1.0f;
            }
        }
    }
    __syncthreads();   // the only barrier

    // ---- phase C: 4 barrier-free row iterations, 4 rules/lane ----
    const int g  = tid >> 5;        // row-group 0..7
    const int jj = tid & 31;        // lane in group
    const unsigned int pk = s_mask32[jj];
    const int r0 = 4 * jj;
    const float4* __restrict__ cq = (const float4*)consequent;

    #pragma unroll
    for (int it = 0; it < 4; ++it) {
        const int rl  = g + 8 * it;
        const int row = base + rl;
        const bool live = (row < nrows);

        const float4 xa0 = *(const float4*)&s_x[rl][0];
        const float4 xa1 = *(const float4*)&s_x[rl][4];
        const float4 mA = *(const float4*)&s_mem[rl][0];
        const float4 mB = *(const float4*)&s_mem[rl][4];
        const float4 mC = *(const float4*)&s_mem[rl][8];
        const float2 mD = *(const float2*)&s_mem[rl][12];

        const float mlo[7] = {mA.x, mA.z, mB.x, mB.z, mC.x, mC.z, mD.x};
        const float mhi[7] = {mA.y, mA.w, mB.y, mB.w, mC.y, mC.w, mD.y};

        // prefix over features 0..4 — shared by this lane's 4 rules
        // (rules 4j..4j+3 differ only in features 5,6 per np.indices order)
        const unsigned int m0 = pk & 0xffu;
        float p0 = (m0 & 1u)  ? mhi[0] : mlo[0];
        float p1 = (m0 & 2u)  ? mhi[1] : mlo[1];
        float p2 = (m0 & 4u)  ? mhi[2] : mlo[2];
        float p3 = (m0 & 8u)  ? mhi[3] : mlo[3];
        float p4 = (m0 & 16u) ? mhi[4] : mlo[4];
        const float P5 = ((p0 * p1) * (p2 * p3)) * p4;
        const float M5 = fminf(fminf(fminf(p0, p1), fminf(p2, p3)), p4);

        float f[4];
        float S = 0.f, dot = 0.f;
        #pragma unroll
        for (int k = 0; k < 4; ++k) {
            const unsigned int mk = pk >> (8 * k);
            const float g5 = (mk & 0x20u) ? mhi[5] : mlo[5];
            const float g6 = (mk & 0x40u) ? mhi[6] : mlo[6];
            const float prod = P5 * (g5 * g6);
            const float mn   = fminf(M5, fminf(g5, g6));
            const float fr   = fmaf(w, prod, w1 * mn);

            const int r = r0 + k;
            const float4 c0 = cq[2 * r];
            const float4 c1 = cq[2 * r + 1];
            float ro = c0.x * xa0.x;
            ro = fmaf(c0.y, xa0.y, ro);
            ro = fmaf(c0.z, xa0.z, ro);
            ro = fmaf(c0.w, xa0.w, ro);
            ro = fmaf(c1.x, xa1.x, ro);
            ro = fmaf(c1.y, xa1.y, ro);
            ro = fmaf(c1.z, xa1.z, ro);
            ro = fmaf(c1.w, xa1.w, ro);

            f[k] = fr;
            S += fr;
            dot = fmaf(fr, ro, dot);
        }

        #pragma unroll
        for (int off = 1; off < 32; off <<= 1) {
            S   += __shfl_xor(S, off, 64);
            dot += __shfl_xor(dot, off, 64);
        }
        const float invS = 1.0f / (S + 1e-8f);

        if (live) {
            float4 nf4;
            nf4.x = f[0] * invS;
            nf4.y = f[1] * invS;
            nf4.z = f[2] * invS;
            nf4.w = f[3] * invS;
            *(float4*)&nf_out[(size_t)row * NR + r0] = nf4;
            if (jj == 0) out[row] = dot * invS;
        }
    }
}

extern "C" void kernel_launch(void* const* d_in, const int* in_sizes, int n_in,
                              void* d_out, int out_size, void* d_ws, size_t ws_size,
                              hipStream_t stream) {
    const float* x     = (const float*)d_in[0];
    const float* mu_g  = (const float*)d_in[1];
    const float* sig_g = (const float*)d_in[2];
    const float* ta    = (const float*)d_in[3];
    const float* tb    = (const float*)d_in[4];
    const float* tc    = (const float*)d_in[5];
    const float* td    = (const float*)d_in[6];
    const float* mfm   = (const float*)d_in[7];
    const float* tnw   = (const float*)d_in[8];
    const float* cons  = (const float*)d_in[9];
    const int*   ridx  = (const int*)d_in[10];

    const int nrows = in_sizes[0] / NF;            // 65536

    float* out     = (float*)d_out;
    float* nf_out  = out + nrows;
    float* mem_out = nf_out + (size_t)nrows * NR;

    const int grid = (nrows + ROWS - 1) / ROWS;
    anfis_kernel<<<grid, 256, 0, stream>>>(x, mu_g, sig_g, ta, tb, tc, td,
                                           mfm, tnw, cons, ridx,
                                           out, nf_out, mem_out, nrows);
}

// Round 4
// 102.372 us; speedup vs baseline: 1.1306x; 1.1306x over previous
//
#include <hip/hip_runtime.h>
#include <math.h>

#define NF 7
#define NR 128
#define RPB 8      // rows per iteration per block
#define ITERS 4    // row-chunks per block

__global__ __launch_bounds__(256) void anfis_kernel(
    const float* __restrict__ x,
    const float* __restrict__ mu_g,
    const float* __restrict__ sig_g,
    const float* __restrict__ ta, const float* __restrict__ tb,
    const float* __restrict__ tc, const float* __restrict__ td,
    const float* __restrict__ mf_mix,
    const float* __restrict__ tnw,
    const float* __restrict__ consequent,   // [128][8]
    const int*   __restrict__ rule_idx,     // [128][7]
    float* __restrict__ out,                // [B]
    float* __restrict__ nf_out,             // [B][128]
    float* __restrict__ mem_out,            // [B][14]
    int nrows)
{
    __shared__ float s_xaug[RPB][8];       // [1, x0..x6]
    __shared__ float s_mem[RPB][16];       // 14 used, padded
    __shared__ unsigned int s_mask32[32];  // 128 rule masks packed 4/word

    const int tid = threadIdx.x;
    const int row_local = tid >> 5;        // 0..7
    const int j = tid & 31;                // lane within row-group

    // ---- once per block: rule masks ----
    if (tid < NR) {
        int m = 0;
        #pragma unroll
        for (int i = 0; i < NF; ++i)
            if (rule_idx[tid * NF + i] != 0) m |= (1 << i);
        ((unsigned char*)s_mask32)[tid] = (unsigned char)m;
    }
    const float alpha = 1.0f / (1.0f + __expf(-mf_mix[0]));
    const float w     = 1.0f / (1.0f + __expf(-tnw[0]));

    // ---- once per block: row-invariant membership params (lanes j<14) ----
    float mu_j = 0.f, i2s2 = 0.f, q0 = 0.f, q1 = 0.f, q2 = 0.f, q3 = 0.f;
    float invL = 0.f, invR = 0.f;
    if (j < 14) {
        mu_j = mu_g[j];
        float sg = fmaxf(sig_g[j], 1e-6f);
        i2s2 = 1.0f / (2.0f * sg * sg);

        float p0 = ta[j], p1 = tb[j], p2 = tc[j], p3 = td[j];
        float lo, hi;
        lo = fminf(p0, p1); hi = fmaxf(p0, p1); p0 = lo; p1 = hi;
        lo = fminf(p2, p3); hi = fmaxf(p2, p3); p2 = lo; p3 = hi;
        lo = fminf(p0, p2); hi = fmaxf(p0, p2); p0 = lo; p2 = hi;
        lo = fminf(p1, p3); hi = fmaxf(p1, p3); p1 = lo; p3 = hi;
        lo = fminf(p1, p2); hi = fmaxf(p1, p2); p1 = lo; p2 = hi;
        q0 = p0; q1 = p1; q2 = p2; q3 = p3;
        invL = 1.0f / (p1 - p0 + 1e-6f);
        invR = 1.0f / (p3 - p2 + 1e-6f);
    }
    const float one_m_alpha = 1.0f - alpha;
    const float one_m_w     = 1.0f - w;

    const int base = blockIdx.x * (RPB * ITERS);
    const float4* __restrict__ cq = (const float4*)consequent;
    const unsigned int pk = s_mask32[0];   // placeholder; real read after barrier

    for (int it = 0; it < ITERS; ++it) {
        const int row = base + it * RPB + row_local;
        const bool live = (row < nrows);

        __syncthreads();   // protect s_xaug/s_mem reuse; makes masks visible on it==0

        // ---- stage x_aug ----
        if (j < NF) s_xaug[row_local][1 + j] = live ? x[row * NF + j] : 0.0f;
        if (j == NF) s_xaug[row_local][0] = 1.0f;

        // ---- membership (lanes j<14), row-variant part only ----
        if (j < 14) {
            const float xi = live ? x[row * NF + (j >> 1)] : 0.0f;
            const float dm = xi - mu_j;
            const float gauss = __expf(-(dm * dm) * i2s2);
            float left  = (xi - q0) * invL;
            left = fminf(fmaxf(left, 0.0f), 1.0f);
            const float flat = (xi >= q1 && xi <= q2) ? 1.0f : 0.0f;
            float right = (q3 - xi) * invR;
            right = fminf(fmaxf(right, 0.0f), 1.0f);
            const float trap = fmaxf(fminf(left, right), flat);
            const float m = fmaf(alpha, gauss, one_m_alpha * trap);
            s_mem[row_local][j] = m;
            if (live) mem_out[row * 14 + j] = m;
        }
        __syncthreads();

        // ---- 4 rules per thread, prefix-factored over features 0..4 ----
        const float4 xa0 = *(const float4*)&s_xaug[row_local][0];
        const float4 xa1 = *(const float4*)&s_xaug[row_local][4];
        const float4 mA = *(const float4*)&s_mem[row_local][0];
        const float4 mB = *(const float4*)&s_mem[row_local][4];
        const float4 mC = *(const float4*)&s_mem[row_local][8];
        const float2 mD = *(const float2*)&s_mem[row_local][12];

        const unsigned int msks = s_mask32[j];
        const int r0 = 4 * j;

        // features 0..4 are constant across this lane's 4 rules
        // (rule r: feature i selects set (r >> (6-i)) & 1; r in {4j..4j+3})
        const unsigned int m0 = msks & 0xffu;
        const float p0 = (m0 & 1u)  ? mA.y : mA.x;
        const float p1 = (m0 & 2u)  ? mA.w : mA.z;
        const float p2 = (m0 & 4u)  ? mB.y : mB.x;
        const float p3 = (m0 & 8u)  ? mB.w : mB.z;
        const float p4 = (m0 & 16u) ? mC.y : mC.x;
        const float P5 = ((p0 * p1) * (p2 * p3)) * p4;
        const float M5 = fminf(fminf(fminf(p0, p1), fminf(p2, p3)), p4);

        float f[4];
        float S = 0.0f, dot = 0.0f;

        #pragma unroll
        for (int k = 0; k < 4; ++k) {
            const unsigned int mk = msks >> (8 * k);
            const float g5 = (mk & 0x20u) ? mC.w : mC.z;
            const float g6 = (mk & 0x40u) ? mD.y : mD.x;
            const float prod = P5 * (g5 * g6);
            const float mn   = fminf(M5, fminf(g5, g6));
            const float fr   = fmaf(w, prod, one_m_w * mn);

            const int r = r0 + k;
            const float4 c0 = cq[2 * r];
            const float4 c1 = cq[2 * r + 1];
            float ro = c0.x * xa0.x;
            ro = fmaf(c0.y, xa0.y, ro);
            ro = fmaf(c0.z, xa0.z, ro);
            ro = fmaf(c0.w, xa0.w, ro);
            ro = fmaf(c1.x, xa1.x, ro);
            ro = fmaf(c1.y, xa1.y, ro);
            ro = fmaf(c1.z, xa1.z, ro);
            ro = fmaf(c1.w, xa1.w, ro);

            f[k] = fr;
            S += fr;
            dot = fmaf(fr, ro, dot);
        }

        // ---- reduce over the 32-lane row-group ----
        #pragma unroll
        for (int off = 1; off < 32; off <<= 1) {
            S   += __shfl_xor(S, off, 64);
            dot += __shfl_xor(dot, off, 64);
        }
        const float invS = 1.0f / (S + 1e-8f);

        if (live) {
            float4 nf4;
            nf4.x = f[0] * invS;
            nf4.y = f[1] * invS;
            nf4.z = f[2] * invS;
            nf4.w = f[3] * invS;
            *(float4*)&nf_out[(size_t)row * NR + r0] = nf4;
            if (j == 0) out[row] = dot * invS;
        }
    }
}

extern "C" void kernel_launch(void* const* d_in, const int* in_sizes, int n_in,
                              void* d_out, int out_size, void* d_ws, size_t ws_size,
                              hipStream_t stream) {
    const float* x     = (const float*)d_in[0];
    const float* mu_g  = (const float*)d_in[1];
    const float* sig_g = (const float*)d_in[2];
    const float* ta    = (const float*)d_in[3];
    const float* tb    = (const float*)d_in[4];
    const float* tc    = (const float*)d_in[5];
    const float* td    = (const float*)d_in[6];
    const float* mfm   = (const float*)d_in[7];
    const float* tnw   = (const float*)d_in[8];
    const float* cons  = (const float*)d_in[9];
    const int*   ridx  = (const int*)d_in[10];

    const int nrows = in_sizes[0] / NF;            // 65536

    float* out     = (float*)d_out;
    float* nf_out  = out + nrows;
    float* mem_out = nf_out + (size_t)nrows * NR;

    const int rows_per_block = RPB * ITERS;
    const int grid = (nrows + rows_per_block - 1) / rows_per_block;
    anfis_kernel<<<grid, 256, 0, stream>>>(x, mu_g, sig_g, ta, tb, tc, td,
                                           mfm, tnw, cons, ridx,
                                           out, nf_out, mem_out, nrows);
}

// Round 6
// 96.154 us; speedup vs baseline: 1.2037x; 1.0647x over previous
//
#include <hip/hip_runtime.h>

#define NF 7
#define NR 128
#define ROWS 64     // rows per block
#define CITERS 8    // phase-C iterations (8 rows each)

typedef float v4f __attribute__((ext_vector_type(4)));

__global__ __launch_bounds__(256) void anfis_kernel(
    const float* __restrict__ x,
    const float* __restrict__ mu_g,  const float* __restrict__ sig_g,
    const float* __restrict__ ta, const float* __restrict__ tb,
    const float* __restrict__ tc, const float* __restrict__ td,
    const float* __restrict__ mf_mix, const float* __restrict__ tnw,
    const float* __restrict__ consequent,   // [128][8]
    const int*   __restrict__ rule_idx,     // [128][7]
    float* __restrict__ out,                // [B]
    float* __restrict__ nf_out,             // [B][128]
    float* __restrict__ mem_out,            // [B][14]
    int nrows)
{
    __shared__ float s_x[ROWS][8];          // [1, x0..x6]
    __shared__ float s_mem[ROWS][16];       // 14 used
    __shared__ unsigned int s_mask32[32];   // 128 rule masks packed 4/word

    const int tid  = threadIdx.x;
    const int base = blockIdx.x * ROWS;

    // ---- phase A: rule masks (once per block) ----
    if (tid < NR) {
        int m = 0;
        #pragma unroll
        for (int i = 0; i < NF; ++i)
            if (rule_idx[tid * NF + i] != 0) m |= (1 << i);
        ((unsigned char*)s_mask32)[tid] = (unsigned char)m;
    }

    const float alpha = 1.0f / (1.0f + __expf(-mf_mix[0]));
    const float w     = 1.0f / (1.0f + __expf(-tnw[0]));
    const float a1 = 1.0f - alpha, w1 = 1.0f - w;

    // ---- phase B: all 64 rows' memberships upfront (4 rows/thread) ----
    {
        const int j   = tid & 15;
        const int r16 = tid >> 4;

        float mu_j = 0.f, i2s2 = 0.f, q0 = 0.f, q1 = 0.f, q2 = 0.f, q3 = 0.f;
        float invL = 0.f, invR = 0.f;
        if (j < 14) {
            mu_j = mu_g[j];
            float sg = fmaxf(sig_g[j], 1e-6f);
            i2s2 = 1.0f / (2.0f * sg * sg);
            float p0 = ta[j], p1 = tb[j], p2 = tc[j], p3 = td[j];
            float lo, hi;
            lo = fminf(p0, p1); hi = fmaxf(p0, p1); p0 = lo; p1 = hi;
            lo = fminf(p2, p3); hi = fmaxf(p2, p3); p2 = lo; p3 = hi;
            lo = fminf(p0, p2); hi = fmaxf(p0, p2); p0 = lo; p2 = hi;
            lo = fminf(p1, p3); hi = fmaxf(p1, p3); p1 = lo; p3 = hi;
            lo = fminf(p1, p2); hi = fmaxf(p1, p2); p1 = lo; p2 = hi;
            q0 = p0; q1 = p1; q2 = p2; q3 = p3;
            invL = 1.0f / (p1 - p0 + 1e-6f);
            invR = 1.0f / (p3 - p2 + 1e-6f);
        }

        #pragma unroll
        for (int h = 0; h < 4; ++h) {
            const int rl  = r16 + 16 * h;
            const int row = base + rl;
            const bool live = (row < nrows);
            if (j < 14) {
                const float xi = live ? x[row * NF + (j >> 1)] : 0.0f;
                const float dm = xi - mu_j;
                const float gauss = __expf(-(dm * dm) * i2s2);
                float left = (xi - q0) * invL;
                left = fminf(fmaxf(left, 0.f), 1.f);
                const float flat = (xi >= q1 && xi <= q2) ? 1.f : 0.f;
                float right = (q3 - xi) * invR;
                right = fminf(fmaxf(right, 0.f), 1.f);
                const float trap = fmaxf(fminf(left, right), flat);
                const float m = fmaf(alpha, gauss, a1 * trap);
                s_mem[rl][j] = m;
                if (live) __builtin_nontemporal_store(m, &mem_out[row * 14 + j]);
                if ((j & 1) == 0) s_x[rl][1 + (j >> 1)] = xi;
            } else if (j == 15) {
                s_x[rl][0] = 1.0f;
            }
        }
    }
    __syncthreads();   // the only barrier

    // ---- phase C: 8 row iterations, 4 rules/lane ----
    const int g  = tid >> 5;        // row-group 0..7
    const int jj = tid & 31;        // lane in group
    const unsigned int msks = s_mask32[jj];
    const int r0 = 4 * jj;
    const float4* __restrict__ cq = (const float4*)consequent;

    // hoist this lane's 4 consequent rows (32 B each) once
    float4 c[8];
    #pragma unroll
    for (int k = 0; k < 8; ++k) c[k] = cq[2 * r0 + k];

    // prefix selectors (features 0..4 constant across this lane's 4 rules)
    const unsigned int m0 = msks & 0xffu;

    #pragma unroll 2
    for (int it = 0; it < CITERS; ++it) {
        const int rl  = g + 8 * it;
        const int row = base + rl;
        const bool live = (row < nrows);

        const float4 xa0 = *(const float4*)&s_x[rl][0];
        const float4 xa1 = *(const float4*)&s_x[rl][4];
        const float4 mA = *(const float4*)&s_mem[rl][0];
        const float4 mB = *(const float4*)&s_mem[rl][4];
        const float4 mC = *(const float4*)&s_mem[rl][8];
        const float2 mD = *(const float2*)&s_mem[rl][12];

        const float p0 = (m0 & 1u)  ? mA.y : mA.x;
        const float p1 = (m0 & 2u)  ? mA.w : mA.z;
        const float p2 = (m0 & 4u)  ? mB.y : mB.x;
        const float p3 = (m0 & 8u)  ? mB.w : mB.z;
        const float p4 = (m0 & 16u) ? mC.y : mC.x;
        const float P5 = ((p0 * p1) * (p2 * p3)) * p4;
        const float M5 = fminf(fminf(fminf(p0, p1), fminf(p2, p3)), p4);

        float f[4];
        float S = 0.f, dot = 0.f;
        #pragma unroll
        for (int k = 0; k < 4; ++k) {
            const unsigned int mk = msks >> (8 * k);
            const float g5 = (mk & 0x20u) ? mC.w : mC.z;
            const float g6 = (mk & 0x40u) ? mD.y : mD.x;
            const float prod = P5 * (g5 * g6);
            const float mn   = fminf(M5, fminf(g5, g6));
            const float fr   = fmaf(w, prod, w1 * mn);

            const float4 c0 = c[2 * k];
            const float4 c1 = c[2 * k + 1];
            float ro = c0.x * xa0.x;
            ro = fmaf(c0.y, xa0.y, ro);
            ro = fmaf(c0.z, xa0.z, ro);
            ro = fmaf(c0.w, xa0.w, ro);
            ro = fmaf(c1.x, xa1.x, ro);
            ro = fmaf(c1.y, xa1.y, ro);
            ro = fmaf(c1.z, xa1.z, ro);
            ro = fmaf(c1.w, xa1.w, ro);

            f[k] = fr;
            S += fr;
            dot = fmaf(fr, ro, dot);
        }

        #pragma unroll
        for (int off = 1; off < 32; off <<= 1) {
            S   += __shfl_xor(S, off, 64);
            dot += __shfl_xor(dot, off, 64);
        }
        const float invS = 1.0f / (S + 1e-8f);

        if (live) {
            v4f nf4;
            nf4.x = f[0] * invS;
            nf4.y = f[1] * invS;
            nf4.z = f[2] * invS;
            nf4.w = f[3] * invS;
            __builtin_nontemporal_store(nf4, (v4f*)&nf_out[(size_t)row * NR + r0]);
            if (jj == 0) out[row] = dot * invS;
        }
    }
}

extern "C" void kernel_launch(void* const* d_in, const int* in_sizes, int n_in,
                              void* d_out, int out_size, void* d_ws, size_t ws_size,
                              hipStream_t stream) {
    const float* x     = (const float*)d_in[0];
    const float* mu_g  = (const float*)d_in[1];
    const float* sig_g = (const float*)d_in[2];
    const float* ta    = (const float*)d_in[3];
    const float* tb    = (const float*)d_in[4];
    const float* tc    = (const float*)d_in[5];
    const float* td    = (const float*)d_in[6];
    const float* mfm   = (const float*)d_in[7];
    const float* tnw   = (const float*)d_in[8];
    const float* cons  = (const float*)d_in[9];
    const int*   ridx  = (const int*)d_in[10];

    const int nrows = in_sizes[0] / NF;            // 65536

    float* out     = (float*)d_out;
    float* nf_out  = out + nrows;
    float* mem_out = nf_out + (size_t)nrows * NR;

    const int grid = (nrows + ROWS - 1) / ROWS;
    anfis_kernel<<<grid, 256, 0, stream>>>(x, mu_g, sig_g, ta, tb, tc, td,
                                           mfm, tnw, cons, ridx,
                                           out, nf_out, mem_out, nrows);
}